// Round 6
// baseline (124.598 us; speedup 1.0000x reference)
//
#include <hip/hip_runtime.h>
#include <hip/hip_bf16.h>
#include <math.h>

#define BATCH 4096
#define NROW  8192
#define DIM   256

// zb holds bf16( sqrt(2*log2e) * z_hat ), so MFMA acc = 2*log2(e)*sim and
// exp(2*sim) == exp2(acc) — one v_exp_f32 per element, no mul.
#define SCALE_IN 1.69864360f              /* sqrt(2*1.4426950408889634) */
#define LN2      0.69314718055994531f     /* converts acc-units back to 2*sim */

typedef __attribute__((ext_vector_type(8))) short  short8;   // 8 bf16 / 4 VGPRs
typedef __attribute__((ext_vector_type(4))) float  floatx4;  // MFMA C/D

// ---------------------------------------------------------------------------
// ws layout:
//   zb     @ 0          : ushort[8192][256]  (4 MiB)  scaled-normalized bf16
//   part   @ 4 MiB      : float[8192]        row+col sums of exp (atomic)
//   bpart  @ 4 MiB+36864: float[2048]        per-block loss partials
// part zeroed by k_prep every call (ws is re-poisoned by the harness; the
// 256 MiB ws poison-fill itself costs ~45 us inside the timed window — fixed
// harness tax, not addressable from here).
// ---------------------------------------------------------------------------

// Wave-per-row: load fp32 row, L2-normalize, scale, write bf16. Also zeroes part.
__global__ __launch_bounds__(256) void k_prep(const float* __restrict__ z1,
                                              const float* __restrict__ z2,
                                              ushort* __restrict__ zb,
                                              float* __restrict__ part) {
  if (threadIdx.x < 4) part[blockIdx.x * 4 + threadIdx.x] = 0.f;

  int row  = blockIdx.x * 4 + (threadIdx.x >> 6);
  int lane = threadIdx.x & 63;
  const float4* src = (row < BATCH) ? (const float4*)(z1 + (size_t)row * DIM)
                                    : (const float4*)(z2 + (size_t)(row - BATCH) * DIM);
  float4 v = src[lane];
  float ss = v.x * v.x + v.y * v.y + v.z * v.z + v.w * v.w;
#pragma unroll
  for (int off = 1; off < 64; off <<= 1) ss += __shfl_xor(ss, off, 64);
  float s = SCALE_IN / fmaxf(sqrtf(ss), 1e-12f);
  __hip_bfloat16 h0 = __float2bfloat16(v.x * s), h1 = __float2bfloat16(v.y * s);
  __hip_bfloat16 h2 = __float2bfloat16(v.z * s), h3 = __float2bfloat16(v.w * s);
  ushort4 hb = {*(ushort*)&h0, *(ushort*)&h1, *(ushort*)&h2, *(ushort*)&h3};
  ((ushort4*)(zb + (size_t)row * DIM))[lane] = hb;
}

// ---------------------------------------------------------------------------
// Symmetric tile kernel, NO LDS STAGING: 528 blocks = upper triangle (r<=c)
// of the 32x32 grid of 256x256 sim tiles. B-fragments are loaded straight
// from global: lane reads 16 B at zb[(col)*256 + quad*8 + k*32] — the wave's
// 64 lanes form 16 rows x 64 B contiguous segments (cache-line coalesced,
// 8 KB/cs working set, L1-resident; zb is 4 MiB, L2/L3-resident). This
// deletes R5's 128 ds_write + 128 ds_read per wave, both barriers, and all
// bank conflicts — LDS gave zero reuse since every wave read the whole tile.
// Wave owns 64 rows: Af[4][8] pinned = 128 VGPRs; live set ~210 VGPR, fits
// (256,2) without spill (R3 lesson). Off-diag tiles also accumulate col sums
// (symmetry) into per-wave LDS scol, one coalesced atomic pass at the end.
// MFMA 16x16x32_bf16: A[m=lane&15][k=quad*8+j]; B[k][n=lane&15];
//                     C/D row=quad*4+reg, col=lane&15.
// ---------------------------------------------------------------------------
__global__ __launch_bounds__(256, 2) void k_simsum(const ushort* __restrict__ zb,
                                                   float* __restrict__ part) {
  __shared__ float scol[4][256];                  // 4 KiB, only LDS left

  // upper-triangle decode on the 32-grid: S(r) = r*(65-r)/2 blocks before row r
  int b = blockIdx.x;
  int r = (int)((65.0f - sqrtf(65.0f * 65.0f - 8.0f * (float)b)) * 0.5f);
  r = (r > 31) ? 31 : ((r < 0) ? 0 : r);
  while ((r + 1) * (65 - (r + 1)) / 2 <= b) r++;
  while (r * (65 - r) / 2 > b) r--;
  int c = r + (b - r * (65 - r) / 2);
  const bool diag = (r == c);

  const int tid  = threadIdx.x;
  const int w    = tid >> 6;
  const int lane = tid & 63;
  const int quad = lane >> 4;
  const int l16  = lane & 15;
  const int rowbase = r * 256 + w * 64;
  const int cbase   = c * 256;

  {
    float* sf = (float*)scol;
    sf[tid] = 0.f; sf[tid + 256] = 0.f; sf[tid + 512] = 0.f; sf[tid + 768] = 0.f;
  }
  __syncthreads();

  // Pin A fragments: 4 rowblocks x 8 k-steps = 128 VGPRs
  short8 Af[4][8];
#pragma unroll
  for (int rb = 0; rb < 4; rb++) {
    const ushort* p = zb + (size_t)(rowbase + rb * 16 + l16) * DIM + quad * 8;
#pragma unroll
    for (int k = 0; k < 8; k++) Af[rb][k] = *(const short8*)(p + k * 32);
  }

  float rsum[4][4];
#pragma unroll
  for (int rb = 0; rb < 4; rb++)
#pragma unroll
    for (int rr = 0; rr < 4; rr++) rsum[rb][rr] = 0.f;

  // B-frag base for this lane: row (cbase + l16), byte offset quad*16
  const ushort* bbase = zb + (size_t)(cbase + l16) * DIM + quad * 8;

#pragma unroll 1
  for (int cs = 0; cs < 16; cs++) {
    const ushort* bp = bbase + (size_t)cs * 16 * DIM;
    short8 Bf[8];
#pragma unroll
    for (int k = 0; k < 8; k++) Bf[k] = *(const short8*)(bp + k * 32);

    floatx4 acc[4];
#pragma unroll
    for (int rb = 0; rb < 4; rb++) acc[rb] = (floatx4){0.f, 0.f, 0.f, 0.f};
#pragma unroll
    for (int k = 0; k < 8; k++)
#pragma unroll
      for (int rb = 0; rb < 4; rb++)
        acc[rb] = __builtin_amdgcn_mfma_f32_16x16x32_bf16(Af[rb][k], Bf[k], acc[rb], 0, 0, 0);

    float ca = 0.f;
#pragma unroll
    for (int rb = 0; rb < 4; rb++)
#pragma unroll
      for (int rr = 0; rr < 4; rr++) {
        float e = __builtin_amdgcn_exp2f(acc[rb][rr]);
        rsum[rb][rr] += e;
        ca += e;
      }
    if (!diag) {
      // ca covers this quad's 16 rows for col (cs*16+l16); fold quads
      ca += __shfl_xor(ca, 16, 64);
      ca += __shfl_xor(ca, 32, 64);
      if (quad == 0)
        scol[w][cs * 16 + l16] += ca;   // 16 lanes -> 16 distinct banks
    }
  }

  // Row sums: reduce over the 16 column-lanes, atomics from l16==0 lanes.
#pragma unroll
  for (int rb = 0; rb < 4; rb++)
#pragma unroll
    for (int rr = 0; rr < 4; rr++) {
      float v = rsum[rb][rr];
#pragma unroll
      for (int off = 1; off < 16; off <<= 1) v += __shfl_xor(v, off, 64);
      if (l16 == 0)
        atomicAdd(&part[rowbase + rb * 16 + quad * 4 + rr], v);
    }

  if (!diag) {
    __syncthreads();
    float v = scol[0][tid] + scol[1][tid] + scol[2][tid] + scol[3][tid];
    atomicAdd(&part[cbase + tid], v);   // 256 coalesced lane-atomics
  }
}

// ---------------------------------------------------------------------------
// Wave-per-row loss term. 2048 blocks x 256 threads (4 rows/block).
//   neg_j = part[j] - exp2(selfdot_acc_j)    (matches the matmul diagonal)
//   t_j   = log(neg_j) - dp_acc_j * ln2      (dp_acc = 2*log2e*sim_pair)
// ---------------------------------------------------------------------------
__global__ __launch_bounds__(256) void k_rowterm(const ushort* __restrict__ zb,
                                                 const float* __restrict__ part,
                                                 float* __restrict__ bpart) {
  int j    = blockIdx.x * 4 + (threadIdx.x >> 6);
  int lane = threadIdx.x & 63;
  int pj   = (j + BATCH) & (NROW - 1);
  ushort4 ua = ((const ushort4*)(zb + (size_t)j  * DIM))[lane];
  ushort4 ub = ((const ushort4*)(zb + (size_t)pj * DIM))[lane];
  uint t;
  float ax, ay, az, aw, bx, by, bz, bw;
  t = (uint)ua.x << 16; ax = *(float*)&t;  t = (uint)ua.y << 16; ay = *(float*)&t;
  t = (uint)ua.z << 16; az = *(float*)&t;  t = (uint)ua.w << 16; aw = *(float*)&t;
  t = (uint)ub.x << 16; bx = *(float*)&t;  t = (uint)ub.y << 16; by = *(float*)&t;
  t = (uint)ub.z << 16; bz = *(float*)&t;  t = (uint)ub.w << 16; bw = *(float*)&t;
  float dp = ax * bx + ay * by + az * bz + aw * bw;
  float sd = ax * ax + ay * ay + az * az + aw * aw;
#pragma unroll
  for (int off = 1; off < 64; off <<= 1) {
    dp += __shfl_xor(dp, off, 64);
    sd += __shfl_xor(sd, off, 64);
  }
  __shared__ float sred[4];
  if (lane == 0) {
    float neg = part[j] - __builtin_amdgcn_exp2f(sd);
    sred[threadIdx.x >> 6] = logf(neg) - dp * LN2;
  }
  __syncthreads();
  if (threadIdx.x == 0)
    bpart[blockIdx.x] = sred[0] + sred[1] + sred[2] + sred[3];
}

__global__ void k_final(const float* __restrict__ bpart, float* __restrict__ out) {
  int t = threadIdx.x;  // 256 threads
  float v = 0.f;
#pragma unroll
  for (int i = 0; i < 8; i++) v += bpart[t + i * 256];
  int lane = t & 63;
#pragma unroll
  for (int off = 1; off < 64; off <<= 1) v += __shfl_xor(v, off, 64);
  __shared__ float sred[4];
  if (lane == 0) sred[t >> 6] = v;
  __syncthreads();
  if (t == 0) out[0] = (sred[0] + sred[1] + sred[2] + sred[3]) / (float)NROW;
}

extern "C" void kernel_launch(void* const* d_in, const int* in_sizes, int n_in,
                              void* d_out, int out_size, void* d_ws, size_t ws_size,
                              hipStream_t stream) {
  const float* z1 = (const float*)d_in[0];
  const float* z2 = (const float*)d_in[1];
  float* out = (float*)d_out;

  char* ws = (char*)d_ws;
  ushort* zb    = (ushort*)ws;                                   // 4 MiB
  float*  part  = (float*)(ws + (size_t)4 * 1024 * 1024);        // 32 KiB
  float*  bpart = (float*)(ws + (size_t)4 * 1024 * 1024 + 36864);

  k_prep<<<NROW / 4, 256, 0, stream>>>(z1, z2, zb, part);
  k_simsum<<<528, 256, 0, stream>>>(zb, part);
  k_rowterm<<<NROW / 4, 256, 0, stream>>>(zb, part, bpart);
  k_final<<<1, 256, 0, stream>>>(bpart, out);
}

// Round 7
// 99.379 us; speedup vs baseline: 1.2538x; 1.2538x over previous
//
#include <hip/hip_runtime.h>
#include <hip/hip_bf16.h>
#include <math.h>

#define BATCH 4096
#define NROW  8192
#define DIM   256

// zb holds bf16( sqrt(2*log2e) * z_hat ), so MFMA acc = 2*log2(e)*sim and
// exp(2*sim) == exp2(acc) — one v_exp_f32 per element, no mul.
#define SCALE_IN 1.69864360f              /* sqrt(2*1.4426950408889634) */
#define LN2      0.69314718055994531f     /* converts acc-units back to 2*sim */

typedef __attribute__((ext_vector_type(8))) short  short8;   // 8 bf16 / 4 VGPRs
typedef __attribute__((ext_vector_type(4))) float  floatx4;  // MFMA C/D

// ---------------------------------------------------------------------------
// ws layout:
//   zb     @ 0          : ushort[8192][256]  (4 MiB)  scaled-normalized bf16
//   part   @ 4 MiB      : float[8192]        row+col sums of exp (atomic)
//   bpart  @ 4 MiB+36864: float[2048]        per-block loss partials
// Fixed harness tax ~55 us/replay (256 MiB ws poison-fill at ~6 TB/s + input
// restore + gaps) — not addressable from here.
// ---------------------------------------------------------------------------

// Wave-per-row: load fp32 row, L2-normalize, scale, write bf16. Also zeroes part.
__global__ __launch_bounds__(256) void k_prep(const float* __restrict__ z1,
                                              const float* __restrict__ z2,
                                              ushort* __restrict__ zb,
                                              float* __restrict__ part) {
  if (threadIdx.x < 4) part[blockIdx.x * 4 + threadIdx.x] = 0.f;

  int row  = blockIdx.x * 4 + (threadIdx.x >> 6);
  int lane = threadIdx.x & 63;
  const float4* src = (row < BATCH) ? (const float4*)(z1 + (size_t)row * DIM)
                                    : (const float4*)(z2 + (size_t)(row - BATCH) * DIM);
  float4 v = src[lane];
  float ss = v.x * v.x + v.y * v.y + v.z * v.z + v.w * v.w;
#pragma unroll
  for (int off = 1; off < 64; off <<= 1) ss += __shfl_xor(ss, off, 64);
  float s = SCALE_IN / fmaxf(sqrtf(ss), 1e-12f);
  __hip_bfloat16 h0 = __float2bfloat16(v.x * s), h1 = __float2bfloat16(v.y * s);
  __hip_bfloat16 h2 = __float2bfloat16(v.z * s), h3 = __float2bfloat16(v.w * s);
  ushort4 hb = {*(ushort*)&h0, *(ushort*)&h1, *(ushort*)&h2, *(ushort*)&h3};
  ((ushort4*)(zb + (size_t)row * DIM))[lane] = hb;
}

// ---------------------------------------------------------------------------
// Symmetric tile kernel: 528 blocks (upper triangle of the 32x32 grid of
// 256x256 sim tiles), 512 THREADS / 8 WAVES per block. 2 blocks/CU x 8 waves
// = 16 waves/CU (4/SIMD) — the latency-hiding fix for R4/R5's 75% idle
// cycles (8 waves/CU couldn't cover the ~200-cyc exp/ds gaps between MFMA
// bursts). Wave owns 32 rows: Af[2][8] = 64 pinned VGPRs — light enough that
// the compiler won't rematerialize A loads (the R6 failure: Af[4][8] at 128
// VGPRs got demoted to in-loop global re-fetch, VGPR_Count=96, 62 us).
// B staged in LDS 64-col chunks (also a pinning guarantee: ds_read can't be
// rematerialized across the barrier). Off-diag tiles accumulate col sums
// (symmetry) in per-wave LDS scol, one coalesced atomic pass at the end.
// MFMA 16x16x32_bf16: A[m=lane&15][k=quad*8+j]; B[k][n=lane&15];
//                     C/D row=quad*4+reg, col=lane&15.
// ---------------------------------------------------------------------------
__global__ __launch_bounds__(512, 4) void k_simsum(const ushort* __restrict__ zb,
                                                   float* __restrict__ part) {
  __shared__ __align__(16) ushort Bt[64 * 264];   // 33792 B, +8 pad
  __shared__ float scol[8][256];                  // 8192 B

  // upper-triangle decode on the 32-grid: S(r) = r*(65-r)/2 blocks before row r
  int b = blockIdx.x;
  int r = (int)((65.0f - sqrtf(65.0f * 65.0f - 8.0f * (float)b)) * 0.5f);
  r = (r > 31) ? 31 : ((r < 0) ? 0 : r);
  while ((r + 1) * (65 - (r + 1)) / 2 <= b) r++;
  while (r * (65 - r) / 2 > b) r--;
  int c = r + (b - r * (65 - r) / 2);
  const bool diag = (r == c);

  const int tid  = threadIdx.x;          // 0..511
  const int w    = tid >> 6;             // wave 0..7
  const int lane = tid & 63;
  const int quad = lane >> 4;
  const int l16  = lane & 15;
  const int rowbase = r * 256 + w * 32;  // wave's 32 rows
  const int cbase   = c * 256;

  {
    float* sf = (float*)scol;
    sf[tid] = 0.f; sf[tid + 512] = 0.f; sf[tid + 1024] = 0.f; sf[tid + 1536] = 0.f;
  }

  // Pin A fragments: 2 rowblocks x 8 k-steps = 64 VGPRs
  short8 Af[2][8];
#pragma unroll
  for (int rb = 0; rb < 2; rb++) {
    const ushort* p = zb + (size_t)(rowbase + rb * 16 + l16) * DIM + quad * 8;
#pragma unroll
    for (int k = 0; k < 8; k++) Af[rb][k] = *(const short8*)(p + k * 32);
  }

  float rsum[2][4];
#pragma unroll
  for (int rb = 0; rb < 2; rb++)
#pragma unroll
    for (int rr = 0; rr < 4; rr++) rsum[rb][rr] = 0.f;

#pragma unroll 1
  for (int ct = 0; ct < 4; ct++) {
    const int c0 = cbase + ct * 64;
    __syncthreads();
    {
      // stage 64 rows x 256 ushort (32 KB) = 2048 uint4, 4 per thread
      const uint4* src = (const uint4*)(zb + (size_t)c0 * DIM);
#pragma unroll
      for (int i = 0; i < 4; i++) {
        int idx = tid + i * 512;
        int rr = idx >> 5, cc = idx & 31;
        *(uint4*)(&Bt[rr * 264 + cc * 8]) = src[rr * 32 + cc];
      }
    }
    __syncthreads();

#pragma unroll
    for (int cs = 0; cs < 4; cs++) {
      const ushort* bp = &Bt[(cs * 16 + l16) * 264 + quad * 8];
      floatx4 acc0 = {0.f, 0.f, 0.f, 0.f};
      floatx4 acc1 = {0.f, 0.f, 0.f, 0.f};
#pragma unroll
      for (int k = 0; k < 8; k++) {
        short8 Bf = *(const short8*)(bp + k * 32);
        acc0 = __builtin_amdgcn_mfma_f32_16x16x32_bf16(Af[0][k], Bf, acc0, 0, 0, 0);
        acc1 = __builtin_amdgcn_mfma_f32_16x16x32_bf16(Af[1][k], Bf, acc1, 0, 0, 0);
      }
      float ca = 0.f;
#pragma unroll
      for (int rr = 0; rr < 4; rr++) {
        float e0 = __builtin_amdgcn_exp2f(acc0[rr]);
        float e1 = __builtin_amdgcn_exp2f(acc1[rr]);
        rsum[0][rr] += e0;
        rsum[1][rr] += e1;
        ca += e0 + e1;
      }
      if (!diag) {
        // ca covers this wave's 32 rows for col (ct*64+cs*16+l16); fold quads
        ca += __shfl_xor(ca, 16, 64);
        ca += __shfl_xor(ca, 32, 64);
        if (quad == 0)
          scol[w][ct * 64 + cs * 16 + l16] += ca;   // 16 lanes, 16 banks
      }
    }
  }

  // Row sums: reduce over the 16 column-lanes, atomics from l16==0 lanes.
#pragma unroll
  for (int rb = 0; rb < 2; rb++)
#pragma unroll
    for (int rr = 0; rr < 4; rr++) {
      float v = rsum[rb][rr];
#pragma unroll
      for (int off = 1; off < 16; off <<= 1) v += __shfl_xor(v, off, 64);
      if (l16 == 0)
        atomicAdd(&part[rowbase + rb * 16 + quad * 4 + rr], v);
    }

  if (!diag) {
    __syncthreads();
    if (tid < 256) {
      float v = 0.f;
#pragma unroll
      for (int ww = 0; ww < 8; ww++) v += scol[ww][tid];
      atomicAdd(&part[cbase + tid], v);   // 256 coalesced lane-atomics
    }
  }
}

// ---------------------------------------------------------------------------
// Wave-per-row loss term. 2048 blocks x 256 threads (4 rows/block).
//   neg_j = part[j] - exp2(selfdot_acc_j)    (matches the matmul diagonal)
//   t_j   = log(neg_j) - dp_acc_j * ln2      (dp_acc = 2*log2e*sim_pair)
// ---------------------------------------------------------------------------
__global__ __launch_bounds__(256) void k_rowterm(const ushort* __restrict__ zb,
                                                 const float* __restrict__ part,
                                                 float* __restrict__ bpart) {
  int j    = blockIdx.x * 4 + (threadIdx.x >> 6);
  int lane = threadIdx.x & 63;
  int pj   = (j + BATCH) & (NROW - 1);
  ushort4 ua = ((const ushort4*)(zb + (size_t)j  * DIM))[lane];
  ushort4 ub = ((const ushort4*)(zb + (size_t)pj * DIM))[lane];
  uint t;
  float ax, ay, az, aw, bx, by, bz, bw;
  t = (uint)ua.x << 16; ax = *(float*)&t;  t = (uint)ua.y << 16; ay = *(float*)&t;
  t = (uint)ua.z << 16; az = *(float*)&t;  t = (uint)ua.w << 16; aw = *(float*)&t;
  t = (uint)ub.x << 16; bx = *(float*)&t;  t = (uint)ub.y << 16; by = *(float*)&t;
  t = (uint)ub.z << 16; bz = *(float*)&t;  t = (uint)ub.w << 16; bw = *(float*)&t;
  float dp = ax * bx + ay * by + az * bz + aw * bw;
  float sd = ax * ax + ay * ay + az * az + aw * aw;
#pragma unroll
  for (int off = 1; off < 64; off <<= 1) {
    dp += __shfl_xor(dp, off, 64);
    sd += __shfl_xor(sd, off, 64);
  }
  __shared__ float sred[4];
  if (lane == 0) {
    float neg = part[j] - __builtin_amdgcn_exp2f(sd);
    sred[threadIdx.x >> 6] = logf(neg) - dp * LN2;
  }
  __syncthreads();
  if (threadIdx.x == 0)
    bpart[blockIdx.x] = sred[0] + sred[1] + sred[2] + sred[3];
}

__global__ void k_final(const float* __restrict__ bpart, float* __restrict__ out) {
  int t = threadIdx.x;  // 256 threads
  float v = 0.f;
#pragma unroll
  for (int i = 0; i < 8; i++) v += bpart[t + i * 256];
  int lane = t & 63;
#pragma unroll
  for (int off = 1; off < 64; off <<= 1) v += __shfl_xor(v, off, 64);
  __shared__ float sred[4];
  if (lane == 0) sred[t >> 6] = v;
  __syncthreads();
  if (t == 0) out[0] = (sred[0] + sred[1] + sred[2] + sred[3]) / (float)NROW;
}

extern "C" void kernel_launch(void* const* d_in, const int* in_sizes, int n_in,
                              void* d_out, int out_size, void* d_ws, size_t ws_size,
                              hipStream_t stream) {
  const float* z1 = (const float*)d_in[0];
  const float* z2 = (const float*)d_in[1];
  float* out = (float*)d_out;

  char* ws = (char*)d_ws;
  ushort* zb    = (ushort*)ws;                                   // 4 MiB
  float*  part  = (float*)(ws + (size_t)4 * 1024 * 1024);        // 32 KiB
  float*  bpart = (float*)(ws + (size_t)4 * 1024 * 1024 + 36864);

  k_prep<<<NROW / 4, 256, 0, stream>>>(z1, z2, zb, part);
  k_simsum<<<528, 512, 0, stream>>>(zb, part);
  k_rowterm<<<NROW / 4, 256, 0, stream>>>(zb, part, bpart);
  k_final<<<1, 256, 0, stream>>>(bpart, out);
}